// Round 4
// baseline (297.481 us; speedup 1.0000x reference)
//
#include <hip/hip_runtime.h>
#include <math.h>

#define BATCH 8
#define HH 1024
#define WW 1024
#define CC 3
#define MTOT (HH*WW*CC)          // 3145728 per batch
#define RSEL 1572864u            // ceil(M/2)
#define NSEG 96                  // blocks per batch in pass1
#define SEGCAP 3072u             // per-block segment capacity (expect ~410 used)

// window: |x| < 2^-6. Median of 3.1M N(0,1) samples is within ~8e-3 (11 sigma).
// Window holds ~39K elems/batch. Exact fallback in refine if it ever misses.
#define U_HI 0xBC800000u         // fmap(+2^-6)
#define U_LO 0x437FFFFFu         // fmap(-2^-6)

// ---- ws layout (bytes); nothing needs pre-zeroing (all slots written unconditionally) ----
#define WS_SCNT_OFF   0u         // 8*96 u32 : per-segment window counts
#define WS_CHI_OFF    4096u      // 8*96 u32 : per-block high counts
#define WS_NPART_OFF  8192u      // 96 f32   : znorm partials
#define WS_THR_OFF    12288u     // 8 u32    : thresholds (u-space)
#define WS_NORM_OFF   12352u     // 1 f32    : total norm
#define WS_BUF_OFF    16384u     // 8*96*SEGCAP u32 = 9.4 MB segments

__device__ __forceinline__ unsigned int fmap(float x) {
    unsigned int b = __float_as_uint(x);
    return (b & 0x80000000u) ? ~b : (b | 0x80000000u);
}

// ---- Pass 1 (fused): per-block atomic-free compaction + high-count; y==8 row does znorm ----
__global__ void pass1_kernel(const float* __restrict__ Y,
                             const float* __restrict__ zabs,
                             unsigned int* __restrict__ buf,
                             unsigned int* __restrict__ scnt,
                             unsigned int* __restrict__ chi,
                             float* __restrict__ npart) {
    const int tid = threadIdx.x;
    const int bx = blockIdx.x;

    if (blockIdx.y == 8) {
        // znorm partial: sum zabs^2 over HH*WW, one partial per block
        float s = 0.f;
        const int n4z = HH * WW / 4;
        for (int i = bx * blockDim.x + tid; i < n4z; i += NSEG * blockDim.x) {
            float4 v = ((const float4*)zabs)[i];
            s += v.x * v.x + v.y * v.y + v.z * v.z + v.w * v.w;
        }
        for (int d = 32; d > 0; d >>= 1) s += __shfl_down(s, d);
        __shared__ float ls[4];
        if ((tid & 63) == 0) ls[tid >> 6] = s;
        __syncthreads();
        if (tid == 0) npart[bx] = ls[0] + ls[1] + ls[2] + ls[3];
        return;
    }

    __shared__ unsigned int lbuf[2048];
    __shared__ unsigned int lcnt;
    __shared__ unsigned int red[4];
    const int b = blockIdx.y;
    if (tid == 0) lcnt = 0u;
    __syncthreads();

    const float4* Y4 = (const float4*)(Y + (size_t)b * MTOT);
    unsigned int* seg = buf + (size_t)(b * NSEG + bx) * SEGCAP;
    const int n4 = MTOT / 4;                  // 786432
    const int stride = NSEG * blockDim.x;     // 24576
    const int iters = n4 / stride;            // 32 exactly
    unsigned int hcnt = 0u;
    unsigned int base = 0u;                   // block-uniform running segment offset

    for (int it = 0; it < iters; it++) {
        int i = it * stride + bx * blockDim.x + tid;
        float4 v = Y4[i];
        unsigned int u;
#define PROC(comp) u = fmap(comp); \
        if (u >= U_HI) hcnt++; \
        else if (u >= U_LO) { unsigned int p = atomicAdd(&lcnt, 1u); if (p < 2048u) lbuf[p] = u; }
        PROC(v.x) PROC(v.y) PROC(v.z) PROC(v.w)
#undef PROC
        __syncthreads();
        unsigned int n = lcnt;                // block-uniform after sync (<= 2047 before overflow)
        if (n >= 1024u) {                     // flush so next iter (<=1024 inserts) can't overflow
            for (unsigned int j = tid; j < n; j += blockDim.x) {
                unsigned int p = base + j;
                if (p < SEGCAP) seg[p] = lbuf[j];
            }
            base += n;                        // may exceed SEGCAP -> fallback in refine
            __syncthreads();
            if (tid == 0) lcnt = 0u;
        }
        __syncthreads();
    }
    unsigned int n = lcnt;
    if (n > 2048u) n = 2048u;
    for (unsigned int j = tid; j < n; j += blockDim.x) {
        unsigned int p = base + j;
        if (p < SEGCAP) seg[p] = lbuf[j];
    }
    base += lcnt;
    if (tid == 0) scnt[b * NSEG + bx] = base;   // unconditional write: no memset needed

    for (int d = 32; d > 0; d >>= 1) hcnt += __shfl_down(hcnt, d);
    if ((tid & 63) == 0) red[tid >> 6] = hcnt;
    __syncthreads();
    if (tid == 0) chi[b * NSEG + bx] = red[0] + red[1] + red[2] + red[3];
}

// ---- Refine: blocks 0..7 = per-batch 3-level radix select; block 8 = norm finalize ----
__global__ void __launch_bounds__(1024) refine_kernel(
        const float* __restrict__ Y,
        const unsigned int* __restrict__ buf,
        const unsigned int* __restrict__ scnt,
        const unsigned int* __restrict__ chi,
        const float* __restrict__ npart,
        unsigned int* __restrict__ thr,
        float* __restrict__ normsum) {
    const int tid = threadIdx.x;

    if (blockIdx.x == 8) {
        if (tid == 0) {
            float s = 0.f;
            for (int i = 0; i < NSEG; i++) s += npart[i];
            *normsum = s;
        }
        return;
    }

    __shared__ unsigned int hist[4096];
    __shared__ unsigned int segoff[NSEG + 1];
    __shared__ unsigned int waveSums[16];
    __shared__ unsigned int selBin, selBase;
    __shared__ unsigned int mode_s, n_s, target_s;
    const int b = blockIdx.x;
    const int lane = tid & 63, wid = tid >> 6;

    if (tid == 0) {
        unsigned int run = 0u, Ch = 0u, mx = 0u;
        for (int j = 0; j < NSEG; j++) {
            segoff[j] = run;
            unsigned int c = scnt[b * NSEG + j];
            if (c > mx) mx = c;
            run += c;
            Ch += chi[b * NSEG + j];
        }
        segoff[NSEG] = run;
        int fb = (mx > SEGCAP) || (Ch >= RSEL) || (Ch + run < RSEL);
        mode_s = (unsigned int)fb;
        n_s = fb ? (unsigned int)MTOT : run;
        target_s = fb ? RSEL : (RSEL - Ch);
    }
    __syncthreads();
    const int fb = (int)mode_s;
    const unsigned int n = n_s;
    unsigned int target = target_s;
    const unsigned int* bseg = buf + (size_t)b * NSEG * SEGCAP;
    const float* Yb = Y + (size_t)b * MTOT;

    unsigned int d1 = 0, d2 = 0;

    for (int level = 0; level < 3; level++) {
        const int nb  = (level < 2) ? 4096 : 256;
        const int bpt = (level < 2) ? 4 : 1;
        for (int i = tid; i < nb; i += 1024) hist[i] = 0u;
        if (tid == 0) { selBin = 0u; selBase = 0u; }
        __syncthreads();
        for (unsigned int i = tid; i < n; i += 1024u) {
            unsigned int u;
            if (fb) {
                u = fmap(Yb[i]);
            } else {
                int lo = 0, hi = NSEG - 1;          // find seg: segoff[j] <= i < segoff[j+1]
                while (lo < hi) { int mid = (lo + hi + 1) >> 1; if (segoff[mid] <= i) lo = mid; else hi = mid - 1; }
                u = bseg[(size_t)lo * SEGCAP + (i - segoff[lo])];
            }
            if (level == 0) {
                atomicAdd(&hist[u >> 20], 1u);
            } else if (level == 1) {
                if ((u >> 20) == d1) atomicAdd(&hist[(u >> 8) & 0xFFFu], 1u);
            } else {
                if ((u >> 8) == ((d1 << 12) | d2)) atomicAdd(&hist[u & 0xFFu], 1u);
            }
        }
        __syncthreads();
        // descending scan + pick
        unsigned int c[4] = {0u, 0u, 0u, 0u};
        unsigned int s = 0u;
        const int nthr = nb / bpt;
        if (tid < nthr)
            for (int k = 0; k < bpt; k++) { c[k] = hist[nb - 1 - (tid * bpt + k)]; s += c[k]; }
        unsigned int incl = s;
        for (int d = 1; d < 64; d <<= 1) {
            unsigned int v = __shfl_up(incl, d);
            if (lane >= d) incl += v;
        }
        if (lane == 63) waveSums[wid] = incl;
        __syncthreads();
        if (tid < 16) {
            unsigned int w = waveSums[tid];
            for (int d = 1; d < 16; d <<= 1) {
                unsigned int v = __shfl_up(w, d);
                if (tid >= d) w += v;
            }
            waveSums[tid] = w;
        }
        __syncthreads();
        incl += (wid > 0) ? waveSums[wid - 1] : 0u;
        unsigned int excl = incl - s;
        if (s > 0u && excl < target && incl >= target) {
            unsigned int run = excl;
            for (int k = 0; k < bpt; k++) {
                if (run + c[k] >= target) {
                    selBin = (unsigned int)(nb - 1 - (tid * bpt + k));
                    selBase = run;
                    break;
                }
                run += c[k];
            }
        }
        __syncthreads();
        if (level == 0) d1 = selBin;
        else if (level == 1) d2 = selBin;
        target -= selBase;
        __syncthreads();
    }
    if (tid == 0) thr[b] = (d1 << 20) | (d2 << 8) | selBin;
}

// ---- Fused: blocks [0,8192) threshold+transpose; blocks [8192,10240) Z0 write ----
__global__ void thresh_z_kernel(const float* __restrict__ Y,
                                const unsigned int* __restrict__ thr,
                                const float* __restrict__ zabs,
                                const float* __restrict__ zang,
                                const float* __restrict__ normsum,
                                float* __restrict__ out,
                                float* __restrict__ outz, int interleaved) {
    if (blockIdx.x < 8192) {
        int p = blockIdx.x * blockDim.x + threadIdx.x;   // [0, 2097152)
        int w4 = p & 255;            // W/4 = 256
        int h  = (p >> 8) & 1023;
        int b  = p >> 18;
        unsigned int tu = thr[b];
        const float4* src = (const float4*)(Y + ((size_t)((b * HH + h) * WW) + (size_t)w4 * 4) * CC);
        float4 a0 = src[0], a1 = src[1], a2 = src[2];
        float4 r0, r1, r2;
        r0.x = (fmap(a0.x) >= tu) ? 1.f : 0.f;
        r0.y = (fmap(a0.w) >= tu) ? 1.f : 0.f;
        r0.z = (fmap(a1.z) >= tu) ? 1.f : 0.f;
        r0.w = (fmap(a2.y) >= tu) ? 1.f : 0.f;
        r1.x = (fmap(a0.y) >= tu) ? 1.f : 0.f;
        r1.y = (fmap(a1.x) >= tu) ? 1.f : 0.f;
        r1.z = (fmap(a1.w) >= tu) ? 1.f : 0.f;
        r1.w = (fmap(a2.z) >= tu) ? 1.f : 0.f;
        r2.x = (fmap(a0.z) >= tu) ? 1.f : 0.f;
        r2.y = (fmap(a1.y) >= tu) ? 1.f : 0.f;
        r2.z = (fmap(a2.x) >= tu) ? 1.f : 0.f;
        r2.w = (fmap(a2.w) >= tu) ? 1.f : 0.f;
        size_t base = ((size_t)(b * CC) * HH + h) * WW;
        ((float4*)(out + base))[w4]                        = r0;
        ((float4*)(out + base + (size_t)HH * WW))[w4]      = r1;
        ((float4*)(out + base + (size_t)2 * HH * WW))[w4]  = r2;
    } else {
        int i = (blockIdx.x - 8192) * blockDim.x + threadIdx.x;  // [0, HH*WW/2)
        float inv = 1.0f / sqrtf(*normsum);
        float2 a = ((const float2*)zabs)[i];
        float2 g = ((const float2*)zang)[i];
        float s0, c0, s1, c1;
        __sincosf(g.x, &s0, &c0);
        __sincosf(g.y, &s1, &c1);
        if (interleaved) {
            float4 o;
            o.x = a.x * c0 * inv; o.y = a.x * s0 * inv;
            o.z = a.y * c1 * inv; o.w = a.y * s1 * inv;
            ((float4*)outz)[i] = o;
        } else {
            float2 o;
            o.x = a.x * c0 * inv; o.y = a.y * c1 * inv;
            ((float2*)outz)[i] = o;
        }
    }
}

extern "C" void kernel_launch(void* const* d_in, const int* in_sizes, int n_in,
                              void* d_out, int out_size, void* d_ws, size_t ws_size,
                              hipStream_t stream) {
    const float* Y    = (const float*)d_in[0];
    const float* zabs = (const float*)d_in[1];
    const float* zang = (const float*)d_in[2];
    float* out = (float*)d_out;

    unsigned char* ws = (unsigned char*)d_ws;
    unsigned int* scnt  = (unsigned int*)(ws + WS_SCNT_OFF);
    unsigned int* chi   = (unsigned int*)(ws + WS_CHI_OFF);
    float*        npart = (float*)(ws + WS_NPART_OFF);
    unsigned int* thr   = (unsigned int*)(ws + WS_THR_OFF);
    float*        norm  = (float*)(ws + WS_NORM_OFF);
    unsigned int* buf   = (unsigned int*)(ws + WS_BUF_OFF);

    dim3 g1(NSEG, 9);
    pass1_kernel<<<g1, 256, 0, stream>>>(Y, zabs, buf, scnt, chi, npart);
    refine_kernel<<<9, 1024, 0, stream>>>(Y, buf, scnt, chi, npart, thr, norm);

    size_t zoff = (size_t)BATCH * CC * HH * WW;   // 25165824
    int zfloats = out_size - (int)zoff;
    int interleaved = (zfloats >= 2 * HH * WW) ? 1 : 0;
    thresh_z_kernel<<<8192 + 2048, 256, 0, stream>>>(
        Y, thr, zabs, zang, norm, out, out + zoff, interleaved);
}

// Round 5
// 244.805 us; speedup vs baseline: 1.2152x; 1.2152x over previous
//
#include <hip/hip_runtime.h>
#include <math.h>

#define BATCH 8
#define HH 1024
#define WW 1024
#define CC 3
#define MTOT (HH*WW*CC)          // 3145728 per batch
#define RSEL 1572864u            // ceil(M/2)
#define NSEG 96                  // blocks per batch in pass1
#define SEGCAP 3072u             // per-block segment capacity (expect ~410 used)

// window: |x| < 2^-6. Median of 3.1M N(0,1) samples is within ~8e-3 (11 sigma).
// Window holds ~39K elems/batch. Exact fallback in refine if it ever misses.
#define U_HI 0xBC800000u         // fmap(+2^-6)
#define U_LO 0x437FFFFFu         // fmap(-2^-6)

// ---- ws layout (bytes); nothing needs pre-zeroing (all slots written unconditionally) ----
#define WS_SCNT_OFF   0u         // 8*96 u32 : per-segment window counts
#define WS_CHI_OFF    4096u      // 8*96 u32 : per-block high counts
#define WS_NPART_OFF  8192u      // 96 f32   : znorm partials
#define WS_THR_OFF    12288u     // 8 u32    : thresholds (u-space)
#define WS_NORM_OFF   12352u     // 1 f32    : total norm
#define WS_BUF_OFF    16384u     // 8*96*SEGCAP u32 = 9.4 MB segments

__device__ __forceinline__ unsigned int fmap(float x) {
    unsigned int b = __float_as_uint(x);
    return (b & 0x80000000u) ? ~b : (b | 0x80000000u);
}

// ---- Pass 1 (fused): per-block atomic-free compaction + high-count; y==8 row does znorm ----
__global__ void pass1_kernel(const float* __restrict__ Y,
                             const float* __restrict__ zabs,
                             unsigned int* __restrict__ buf,
                             unsigned int* __restrict__ scnt,
                             unsigned int* __restrict__ chi,
                             float* __restrict__ npart) {
    const int tid = threadIdx.x;
    const int bx = blockIdx.x;

    if (blockIdx.y == 8) {
        // znorm partial: sum zabs^2 over HH*WW, one partial per block
        float s = 0.f;
        const int n4z = HH * WW / 4;
        for (int i = bx * blockDim.x + tid; i < n4z; i += NSEG * blockDim.x) {
            float4 v = ((const float4*)zabs)[i];
            s += v.x * v.x + v.y * v.y + v.z * v.z + v.w * v.w;
        }
        for (int d = 32; d > 0; d >>= 1) s += __shfl_down(s, d);
        __shared__ float ls[4];
        if ((tid & 63) == 0) ls[tid >> 6] = s;
        __syncthreads();
        if (tid == 0) npart[bx] = ls[0] + ls[1] + ls[2] + ls[3];
        return;
    }

    __shared__ unsigned int lbuf[2048];
    __shared__ unsigned int lcnt;
    __shared__ unsigned int red[4];
    const int b = blockIdx.y;
    if (tid == 0) lcnt = 0u;
    __syncthreads();

    const float4* Y4 = (const float4*)(Y + (size_t)b * MTOT);
    unsigned int* seg = buf + (size_t)(b * NSEG + bx) * SEGCAP;
    const int n4 = MTOT / 4;                  // 786432
    const int stride = NSEG * blockDim.x;     // 24576
    const int iters = n4 / stride;            // 32 exactly
    unsigned int hcnt = 0u;
    unsigned int base = 0u;                   // block-uniform running segment offset

    for (int it = 0; it < iters; it++) {
        int i = it * stride + bx * blockDim.x + tid;
        float4 v = Y4[i];
        unsigned int u;
#define PROC(comp) u = fmap(comp); \
        if (u >= U_HI) hcnt++; \
        else if (u >= U_LO) { unsigned int p = atomicAdd(&lcnt, 1u); if (p < 2048u) lbuf[p] = u; }
        PROC(v.x) PROC(v.y) PROC(v.z) PROC(v.w)
#undef PROC
        __syncthreads();
        unsigned int n = lcnt;                // block-uniform after sync (<= 2047 before overflow)
        if (n >= 1024u) {                     // flush so next iter (<=1024 inserts) can't overflow
            for (unsigned int j = tid; j < n; j += blockDim.x) {
                unsigned int p = base + j;
                if (p < SEGCAP) seg[p] = lbuf[j];
            }
            base += n;                        // may exceed SEGCAP -> fallback in refine
            __syncthreads();
            if (tid == 0) lcnt = 0u;
        }
        __syncthreads();
    }
    unsigned int n = lcnt;
    if (n > 2048u) n = 2048u;
    for (unsigned int j = tid; j < n; j += blockDim.x) {
        unsigned int p = base + j;
        if (p < SEGCAP) seg[p] = lbuf[j];
    }
    base += lcnt;
    if (tid == 0) scnt[b * NSEG + bx] = base;   // unconditional write: no memset needed

    for (int d = 32; d > 0; d >>= 1) hcnt += __shfl_down(hcnt, d);
    if ((tid & 63) == 0) red[tid >> 6] = hcnt;
    __syncthreads();
    if (tid == 0) chi[b * NSEG + bx] = red[0] + red[1] + red[2] + red[3];
}

// ---- Refine: blocks 0..7 = per-batch 3-level radix select; block 8 = norm finalize ----
// Gather strategy: wave w processes segments w, w+16, ... lanes stride inside a
// segment -> coalesced independent loads, NO per-element binary search (the R4
// dependent LDS-chain gather cost ~90us; this is the fix).
__global__ void __launch_bounds__(1024) refine_kernel(
        const float* __restrict__ Y,
        const unsigned int* __restrict__ buf,
        const unsigned int* __restrict__ scnt,
        const unsigned int* __restrict__ chi,
        const float* __restrict__ npart,
        unsigned int* __restrict__ thr,
        float* __restrict__ normsum) {
    const int tid = threadIdx.x;

    if (blockIdx.x == 8) {
        if (tid == 0) {
            float s = 0.f;
            for (int i = 0; i < NSEG; i++) s += npart[i];
            *normsum = s;
        }
        return;
    }

    __shared__ unsigned int hist[4096];
    __shared__ unsigned int segcnt[NSEG];
    __shared__ unsigned int waveSums[16];
    __shared__ unsigned int selBin, selBase;
    __shared__ unsigned int mode_s, target_s;
    const int b = blockIdx.x;
    const int lane = tid & 63, wid = tid >> 6;

    if (tid < NSEG) {
        unsigned int c = scnt[b * NSEG + tid];
        segcnt[tid] = (c > SEGCAP) ? SEGCAP : c;
    }
    if (tid == 0) {
        unsigned int tot = 0u, Ch = 0u, mx = 0u;
        for (int j = 0; j < NSEG; j++) {
            unsigned int c = scnt[b * NSEG + j];
            if (c > mx) mx = c;
            tot += c;
            Ch += chi[b * NSEG + j];
        }
        int fb = (mx > SEGCAP) || (Ch >= RSEL) || (Ch + tot < RSEL);
        mode_s = (unsigned int)fb;
        target_s = fb ? RSEL : (RSEL - Ch);
    }
    __syncthreads();
    const int fb = (int)mode_s;
    unsigned int target = target_s;
    const unsigned int* bseg = buf + (size_t)b * NSEG * SEGCAP;
    const float* Yb = Y + (size_t)b * MTOT;

    unsigned int d1 = 0, d2 = 0;

    for (int level = 0; level < 3; level++) {
        const int nb  = (level < 2) ? 4096 : 256;
        const int bpt = (level < 2) ? 4 : 1;
        for (int i = tid; i < nb; i += 1024) hist[i] = 0u;
        if (tid == 0) { selBin = 0u; selBase = 0u; }
        __syncthreads();

#define HISTO(u) do { \
            if (level == 0) atomicAdd(&hist[(u) >> 20], 1u); \
            else if (level == 1) { if (((u) >> 20) == d1) atomicAdd(&hist[((u) >> 8) & 0xFFFu], 1u); } \
            else { if (((u) >> 8) == ((d1 << 12) | d2)) atomicAdd(&hist[(u) & 0xFFu], 1u); } \
        } while (0)

        if (fb) {
            for (unsigned int i = tid; i < (unsigned int)MTOT; i += 1024u) {
                unsigned int u = fmap(Yb[i]);
                HISTO(u);
            }
        } else {
            for (int sj = wid; sj < NSEG; sj += 16) {
                const unsigned int cj = segcnt[sj];
                const unsigned int* sp = bseg + (size_t)sj * SEGCAP;
                for (unsigned int k = lane; k < cj; k += 64u) {
                    unsigned int u = sp[k];
                    HISTO(u);
                }
            }
        }
#undef HISTO
        __syncthreads();
        // descending scan + pick
        unsigned int c[4] = {0u, 0u, 0u, 0u};
        unsigned int s = 0u;
        const int nthr = nb / bpt;
        if (tid < nthr)
            for (int k = 0; k < bpt; k++) { c[k] = hist[nb - 1 - (tid * bpt + k)]; s += c[k]; }
        unsigned int incl = s;
        for (int d = 1; d < 64; d <<= 1) {
            unsigned int v = __shfl_up(incl, d);
            if (lane >= d) incl += v;
        }
        if (lane == 63) waveSums[wid] = incl;
        __syncthreads();
        if (tid < 16) {
            unsigned int w = waveSums[tid];
            for (int d = 1; d < 16; d <<= 1) {
                unsigned int v = __shfl_up(w, d);
                if (tid >= d) w += v;
            }
            waveSums[tid] = w;
        }
        __syncthreads();
        incl += (wid > 0) ? waveSums[wid - 1] : 0u;
        unsigned int excl = incl - s;
        if (s > 0u && excl < target && incl >= target) {
            unsigned int run = excl;
            for (int k = 0; k < bpt; k++) {
                if (run + c[k] >= target) {
                    selBin = (unsigned int)(nb - 1 - (tid * bpt + k));
                    selBase = run;
                    break;
                }
                run += c[k];
            }
        }
        __syncthreads();
        if (level == 0) d1 = selBin;
        else if (level == 1) d2 = selBin;
        target -= selBase;
        __syncthreads();
    }
    if (tid == 0) thr[b] = (d1 << 20) | (d2 << 8) | selBin;
}

// ---- Fused: blocks [0,8192) threshold+transpose; blocks [8192,10240) Z0 write ----
__global__ void thresh_z_kernel(const float* __restrict__ Y,
                                const unsigned int* __restrict__ thr,
                                const float* __restrict__ zabs,
                                const float* __restrict__ zang,
                                const float* __restrict__ normsum,
                                float* __restrict__ out,
                                float* __restrict__ outz, int interleaved) {
    if (blockIdx.x < 8192) {
        int p = blockIdx.x * blockDim.x + threadIdx.x;   // [0, 2097152)
        int w4 = p & 255;            // W/4 = 256
        int h  = (p >> 8) & 1023;
        int b  = p >> 18;
        unsigned int tu = thr[b];
        const float4* src = (const float4*)(Y + ((size_t)((b * HH + h) * WW) + (size_t)w4 * 4) * CC);
        float4 a0 = src[0], a1 = src[1], a2 = src[2];
        float4 r0, r1, r2;
        r0.x = (fmap(a0.x) >= tu) ? 1.f : 0.f;
        r0.y = (fmap(a0.w) >= tu) ? 1.f : 0.f;
        r0.z = (fmap(a1.z) >= tu) ? 1.f : 0.f;
        r0.w = (fmap(a2.y) >= tu) ? 1.f : 0.f;
        r1.x = (fmap(a0.y) >= tu) ? 1.f : 0.f;
        r1.y = (fmap(a1.x) >= tu) ? 1.f : 0.f;
        r1.z = (fmap(a1.w) >= tu) ? 1.f : 0.f;
        r1.w = (fmap(a2.z) >= tu) ? 1.f : 0.f;
        r2.x = (fmap(a0.z) >= tu) ? 1.f : 0.f;
        r2.y = (fmap(a1.y) >= tu) ? 1.f : 0.f;
        r2.z = (fmap(a2.x) >= tu) ? 1.f : 0.f;
        r2.w = (fmap(a2.w) >= tu) ? 1.f : 0.f;
        size_t base = ((size_t)(b * CC) * HH + h) * WW;
        ((float4*)(out + base))[w4]                        = r0;
        ((float4*)(out + base + (size_t)HH * WW))[w4]      = r1;
        ((float4*)(out + base + (size_t)2 * HH * WW))[w4]  = r2;
    } else {
        int i = (blockIdx.x - 8192) * blockDim.x + threadIdx.x;  // [0, HH*WW/2)
        float inv = 1.0f / sqrtf(*normsum);
        float2 a = ((const float2*)zabs)[i];
        float2 g = ((const float2*)zang)[i];
        float s0, c0, s1, c1;
        __sincosf(g.x, &s0, &c0);
        __sincosf(g.y, &s1, &c1);
        if (interleaved) {
            float4 o;
            o.x = a.x * c0 * inv; o.y = a.x * s0 * inv;
            o.z = a.y * c1 * inv; o.w = a.y * s1 * inv;
            ((float4*)outz)[i] = o;
        } else {
            float2 o;
            o.x = a.x * c0 * inv; o.y = a.y * c1 * inv;
            ((float2*)outz)[i] = o;
        }
    }
}

extern "C" void kernel_launch(void* const* d_in, const int* in_sizes, int n_in,
                              void* d_out, int out_size, void* d_ws, size_t ws_size,
                              hipStream_t stream) {
    const float* Y    = (const float*)d_in[0];
    const float* zabs = (const float*)d_in[1];
    const float* zang = (const float*)d_in[2];
    float* out = (float*)d_out;

    unsigned char* ws = (unsigned char*)d_ws;
    unsigned int* scnt  = (unsigned int*)(ws + WS_SCNT_OFF);
    unsigned int* chi   = (unsigned int*)(ws + WS_CHI_OFF);
    float*        npart = (float*)(ws + WS_NPART_OFF);
    unsigned int* thr   = (unsigned int*)(ws + WS_THR_OFF);
    float*        norm  = (float*)(ws + WS_NORM_OFF);
    unsigned int* buf   = (unsigned int*)(ws + WS_BUF_OFF);

    dim3 g1(NSEG, 9);
    pass1_kernel<<<g1, 256, 0, stream>>>(Y, zabs, buf, scnt, chi, npart);
    refine_kernel<<<9, 1024, 0, stream>>>(Y, buf, scnt, chi, npart, thr, norm);

    size_t zoff = (size_t)BATCH * CC * HH * WW;   // 25165824
    int zfloats = out_size - (int)zoff;
    int interleaved = (zfloats >= 2 * HH * WW) ? 1 : 0;
    thresh_z_kernel<<<8192 + 2048, 256, 0, stream>>>(
        Y, thr, zabs, zang, norm, out, out + zoff, interleaved);
}